// Round 1
// baseline (4020.100 us; speedup 1.0000x reference)
//
#include <hip/hip_runtime.h>
#include <hip/hip_bf16.h>

#define NB 8
#define SQ 4096
#define DM 1280
#define NH 20
#define DH 64
#define SE 77
#define SS 4
#define CE 768
#define SKV 81
#define KVP 96   // padded KV rows in workspace buffer

// ---------------------------------------------------------------------------
// Kernel 1: K/V projection for encoder rows 0..76.
// grid (DM/64, NB), 256 threads. BM=80 (rows >=77 zero-src, stores guarded).
// ---------------------------------------------------------------------------
__global__ __launch_bounds__(256) void kv_proj_kernel(
    const float* __restrict__ ehs, const float* __restrict__ Wk,
    const float* __restrict__ Wv, float* __restrict__ Kb, float* __restrict__ Vb)
{
  const int n0 = blockIdx.x * 64;
  const int b  = blockIdx.y;
  const int tid = threadIdx.x;
  const int tx = tid & 15, ty = tid >> 4;
  const int r0 = ty * 5, c0 = tx * 4;

  __shared__ float sS[80][33];   // +1 pad: a-reads 2-way max
  __shared__ float sK[32][64];
  __shared__ float sV[32][64];

  float accK[5][4] = {};
  float accV[5][4] = {};

  for (int kc = 0; kc < CE; kc += 32) {
    __syncthreads();
    for (int f = tid; f < 640; f += 256) {           // 80 rows x 8 float4
      int row = f >> 3, c4 = (f & 7) << 2;
      float4 v = make_float4(0.f, 0.f, 0.f, 0.f);
      if (row < SE) v = *(const float4*)&ehs[(size_t)(b * SE + row) * CE + kc + c4];
      sS[row][c4 + 0] = v.x; sS[row][c4 + 1] = v.y;
      sS[row][c4 + 2] = v.z; sS[row][c4 + 3] = v.w;
    }
    for (int f = tid; f < 512; f += 256) {           // 32 x 16 float4
      int r = f >> 4, c4 = (f & 15) << 2;
      *(float4*)&sK[r][c4] = *(const float4*)&Wk[(size_t)(kc + r) * DM + n0 + c4];
      *(float4*)&sV[r][c4] = *(const float4*)&Wv[(size_t)(kc + r) * DM + n0 + c4];
    }
    __syncthreads();
    #pragma unroll
    for (int k = 0; k < 32; ++k) {
      float a[5];
      #pragma unroll
      for (int i = 0; i < 5; ++i) a[i] = sS[r0 + i][k];
      float4 wk4 = *(float4*)&sK[k][c0];
      float4 wv4 = *(float4*)&sV[k][c0];
      float wk[4] = {wk4.x, wk4.y, wk4.z, wk4.w};
      float wv[4] = {wv4.x, wv4.y, wv4.z, wv4.w};
      #pragma unroll
      for (int i = 0; i < 5; ++i)
        #pragma unroll
        for (int j = 0; j < 4; ++j) {
          accK[i][j] += a[i] * wk[j];
          accV[i][j] += a[i] * wv[j];
        }
    }
  }
  #pragma unroll
  for (int i = 0; i < 5; ++i) {
    int r = r0 + i;
    if (r < SE) {
      *(float4*)&Kb[(size_t)(b * KVP + r) * DM + n0 + c0] =
          make_float4(accK[i][0], accK[i][1], accK[i][2], accK[i][3]);
      *(float4*)&Vb[(size_t)(b * KVP + r) * DM + n0 + c0] =
          make_float4(accV[i][0], accV[i][1], accV[i][2], accV[i][3]);
    }
  }
}

// ---------------------------------------------------------------------------
// Kernel 2: style-token K/V projection (rows 77..80). grid (DM/64, NB).
// ---------------------------------------------------------------------------
__global__ __launch_bounds__(256) void style_proj_kernel(
    const float* __restrict__ sty, const float* __restrict__ Wks,
    const float* __restrict__ Wvs, float* __restrict__ Kb, float* __restrict__ Vb)
{
  const int n0 = blockIdx.x * 64;
  const int b  = blockIdx.y;
  const int tid = threadIdx.x;
  __shared__ float sT[SS][CE];
  for (int f = tid; f < SS * (CE / 4); f += 256) {
    int row = f / (CE / 4), c4 = (f % (CE / 4)) << 2;
    *(float4*)&sT[row][c4] = *(const float4*)&sty[(size_t)(b * SS + row) * CE + c4];
  }
  __syncthreads();
  const int row = tid >> 6;            // wave-uniform -> LDS broadcast reads
  const int col = n0 + (tid & 63);
  float aK = 0.f, aV = 0.f;
  for (int c = 0; c < CE; ++c) {
    float s = sT[row][c];
    aK += s * Wks[(size_t)c * DM + col];
    aV += s * Wvs[(size_t)c * DM + col];
  }
  Kb[(size_t)(b * KVP + SE + row) * DM + col] = aK;   // STYLE_SCALE == 1.0
  Vb[(size_t)(b * KVP + SE + row) * DM + col] = aV;
}

// ---------------------------------------------------------------------------
// Kernel 3: fused Q-projection + attention. grid (SQ/64, NH, NB), 256 threads.
// Phase A: Q tile [64 q][64 d] = hs_tile @ Wq[:, h*64:+64]   (107 GFLOP total)
// Phase B: scores [64 q][81 k] (Q pre-scaled by 1/8)
// softmax per q-row (wave 0) overlapped with V staging
// Phase C: O tile = P @ V, written unnormalized then scaled by 1/sum
// LDS unioned: scores alias the phase-A staging buffers (59.9 KB total).
// ---------------------------------------------------------------------------
__global__ __launch_bounds__(256) void fused_q_attn_kernel(
    const float* __restrict__ hs, const float* __restrict__ Wq,
    const float* __restrict__ Kb, const float* __restrict__ Vb,
    float* __restrict__ Ob)
{
  const int q0 = blockIdx.x * 64;
  const int h  = blockIdx.y;
  const int b  = blockIdx.z;
  const int tid = threadIdx.x;
  const int tx = tid & 15, ty = tid >> 4;
  const int r0 = ty * 4, c0 = tx * 4;

  __shared__ __align__(16) char smem[59904];
  float (*hsL)[33] = (float(*)[33])smem;             // 64x33  (8448 B)
  float (*wqL)[64] = (float(*)[64])(smem + 8448);    // 32x64  (8192 B)
  float (*sL)[85]  = (float(*)[85])smem;             // 64x85  (21760 B) aliases A-stage
  float (*qL)[65]  = (float(*)[65])(smem + 21760);   // 64x65  (16640 B)
  float (*kvL)[64] = (float(*)[64])(smem + 38400);   // 84x64  (21504 B)

  // ---- Phase A: Q tile ----
  float acc[4][4] = {};
  for (int kc = 0; kc < DM; kc += 32) {
    __syncthreads();
    for (int f = tid; f < 512; f += 256) {           // hs chunk 64x32
      int row = f >> 3, c4 = (f & 7) << 2;
      float4 v = *(const float4*)&hs[(size_t)(b * SQ + q0 + row) * DM + kc + c4];
      hsL[row][c4 + 0] = v.x; hsL[row][c4 + 1] = v.y;
      hsL[row][c4 + 2] = v.z; hsL[row][c4 + 3] = v.w;
    }
    for (int f = tid; f < 512; f += 256) {           // Wq chunk 32x64
      int r = f >> 4, c4 = (f & 15) << 2;
      *(float4*)&wqL[r][c4] = *(const float4*)&Wq[(size_t)(kc + r) * DM + h * DH + c4];
    }
    __syncthreads();
    #pragma unroll
    for (int k = 0; k < 32; ++k) {
      float a0 = hsL[r0 + 0][k], a1 = hsL[r0 + 1][k];
      float a2 = hsL[r0 + 2][k], a3 = hsL[r0 + 3][k];
      float4 w4 = *(float4*)&wqL[k][c0];
      float wj[4] = {w4.x, w4.y, w4.z, w4.w};
      #pragma unroll
      for (int j = 0; j < 4; ++j) {
        acc[0][j] += a0 * wj[j];
        acc[1][j] += a1 * wj[j];
        acc[2][j] += a2 * wj[j];
        acc[3][j] += a3 * wj[j];
      }
    }
  }
  // Q -> LDS (pre-scaled by 1/sqrt(dh)=0.125); stage K (pad rows 81..83 = 0)
  #pragma unroll
  for (int i = 0; i < 4; ++i)
    #pragma unroll
    for (int j = 0; j < 4; ++j)
      qL[r0 + i][c0 + j] = acc[i][j] * 0.125f;
  for (int f = tid; f < 84 * 16; f += 256) {
    int kk = f >> 4, d4 = (f & 15) << 2;
    float4 v = make_float4(0.f, 0.f, 0.f, 0.f);
    if (kk < SKV) v = *(const float4*)&Kb[(size_t)(b * KVP + kk) * DM + h * DH + d4];
    *(float4*)&kvL[kk][d4] = v;
  }
  __syncthreads();

  // ---- Phase B: scores. lane = q-row; wave w handles k = w, w+4, ... ----
  const int lane = tid & 63, w = tid >> 6;
  float sc[21];
  #pragma unroll
  for (int i = 0; i < 21; ++i) sc[i] = 0.f;
  #pragma unroll
  for (int d = 0; d < DH; d += 4) {
    float qv0 = qL[lane][d + 0], qv1 = qL[lane][d + 1];
    float qv2 = qL[lane][d + 2], qv3 = qL[lane][d + 3];
    #pragma unroll
    for (int ki = 0; ki < 21; ++ki) {                // k<=83 hits zero pad rows
      float4 kv = *(float4*)&kvL[w + 4 * ki][d];     // wave-uniform: broadcast
      sc[ki] += qv0 * kv.x + qv1 * kv.y + qv2 * kv.z + qv3 * kv.w;
    }
  }
  #pragma unroll
  for (int ki = 0; ki < 21; ++ki) sL[lane][w + 4 * ki] = sc[ki];
  __syncthreads();

  // ---- V staging (all threads) + softmax (wave 0) ----
  for (int f = tid; f < SKV * 16; f += 256) {
    int kk = f >> 4, d4 = (f & 15) << 2;
    *(float4*)&kvL[kk][d4] = *(const float4*)&Vb[(size_t)(b * KVP + kk) * DM + h * DH + d4];
  }
  if (tid < 64) {
    float m = -1e30f;
    for (int k = 0; k < SKV; ++k) m = fmaxf(m, sL[tid][k]);
    float sum = 0.f;
    for (int k = 0; k < SKV; ++k) {
      float e = __expf(sL[tid][k] - m);
      sL[tid][k] = e;
      sum += e;
    }
    sL[tid][84] = 1.0f / sum;      // normalization factor, applied in phase C
  }
  __syncthreads();

  // ---- Phase C: O = P @ V ----
  float o[4][4] = {};
  for (int k = 0; k < SKV; ++k) {
    float p0 = sL[r0 + 0][k], p1 = sL[r0 + 1][k];
    float p2 = sL[r0 + 2][k], p3 = sL[r0 + 3][k];
    float4 v4 = *(float4*)&kvL[k][c0];
    float vj[4] = {v4.x, v4.y, v4.z, v4.w};
    #pragma unroll
    for (int j = 0; j < 4; ++j) {
      o[0][j] += p0 * vj[j];
      o[1][j] += p1 * vj[j];
      o[2][j] += p2 * vj[j];
      o[3][j] += p3 * vj[j];
    }
  }
  #pragma unroll
  for (int i = 0; i < 4; ++i) {
    float inv = sL[r0 + i][84];
    *(float4*)&Ob[(size_t)(b * SQ + q0 + r0 + i) * DM + h * DH + c0] =
        make_float4(o[i][0] * inv, o[i][1] * inv, o[i][2] * inv, o[i][3] * inv);
  }
}

// ---------------------------------------------------------------------------
// Kernel 4: output projection + bias. 128x128x16 fp32 tiles, 2x2 of 4x4 micro.
// grid (DM/128, NB*SQ/128), 256 threads.
// ---------------------------------------------------------------------------
__global__ __launch_bounds__(256) void out_proj_kernel(
    const float* __restrict__ A, const float* __restrict__ Wo,
    const float* __restrict__ bo, float* __restrict__ out)
{
  const int n0 = blockIdx.x * 128;
  const int m0 = blockIdx.y * 128;
  const int tid = threadIdx.x;
  const int tx = tid & 15, ty = tid >> 4;

  __shared__ float aT[16][132];   // A transposed, pad 132 -> conflict-free
  __shared__ float bL[16][128];

  float acc[2][2][4][4] = {};

  for (int kk = 0; kk < DM; kk += 16) {
    __syncthreads();
    #pragma unroll
    for (int u = 0; u < 2; ++u) {
      int f = tid + u * 256;
      {  // A tile 128x16, store transposed
        int row = f >> 2, c4 = (f & 3) << 2;
        float4 av = *(const float4*)&A[(size_t)(m0 + row) * DM + kk + c4];
        aT[c4 + 0][row] = av.x; aT[c4 + 1][row] = av.y;
        aT[c4 + 2][row] = av.z; aT[c4 + 3][row] = av.w;
      }
      {  // B tile 16x128
        int r = f >> 5, c4 = (f & 31) << 2;
        *(float4*)&bL[r][c4] = *(const float4*)&Wo[(size_t)(kk + r) * DM + n0 + c4];
      }
    }
    __syncthreads();
    #pragma unroll
    for (int k = 0; k < 16; ++k) {
      float4 a04 = *(float4*)&aT[k][ty * 4];
      float4 a14 = *(float4*)&aT[k][ty * 4 + 64];
      float4 b04 = *(float4*)&bL[k][tx * 4];
      float4 b14 = *(float4*)&bL[k][tx * 4 + 64];
      float a0[4] = {a04.x, a04.y, a04.z, a04.w};
      float a1[4] = {a14.x, a14.y, a14.z, a14.w};
      float b0[4] = {b04.x, b04.y, b04.z, b04.w};
      float b1[4] = {b14.x, b14.y, b14.z, b14.w};
      #pragma unroll
      for (int i = 0; i < 4; ++i)
        #pragma unroll
        for (int j = 0; j < 4; ++j) {
          acc[0][0][i][j] += a0[i] * b0[j];
          acc[0][1][i][j] += a0[i] * b1[j];
          acc[1][0][i][j] += a1[i] * b0[j];
          acc[1][1][i][j] += a1[i] * b1[j];
        }
    }
  }

  float4 bi0 = *(const float4*)&bo[n0 + tx * 4];
  float4 bi1 = *(const float4*)&bo[n0 + tx * 4 + 64];
  float bias0[4] = {bi0.x, bi0.y, bi0.z, bi0.w};
  float bias1[4] = {bi1.x, bi1.y, bi1.z, bi1.w};

  #pragma unroll
  for (int rb = 0; rb < 2; ++rb) {
    #pragma unroll
    for (int i = 0; i < 4; ++i) {
      int row = m0 + ty * 4 + rb * 64 + i;
      float4 v0 = make_float4(acc[rb][0][i][0] + bias0[0], acc[rb][0][i][1] + bias0[1],
                              acc[rb][0][i][2] + bias0[2], acc[rb][0][i][3] + bias0[3]);
      float4 v1 = make_float4(acc[rb][1][i][0] + bias1[0], acc[rb][1][i][1] + bias1[1],
                              acc[rb][1][i][2] + bias1[2], acc[rb][1][i][3] + bias1[3]);
      *(float4*)&out[(size_t)row * DM + n0 + tx * 4]      = v0;
      *(float4*)&out[(size_t)row * DM + n0 + tx * 4 + 64] = v1;
    }
  }
}

// ---------------------------------------------------------------------------
extern "C" void kernel_launch(void* const* d_in, const int* in_sizes, int n_in,
                              void* d_out, int out_size, void* d_ws, size_t ws_size,
                              hipStream_t stream) {
  const float* hs  = (const float*)d_in[0];
  const float* ehs = (const float*)d_in[1];
  const float* sty = (const float*)d_in[2];
  const float* Wq  = (const float*)d_in[3];
  const float* Wk  = (const float*)d_in[4];
  const float* Wv  = (const float*)d_in[5];
  const float* Wks = (const float*)d_in[6];
  const float* Wvs = (const float*)d_in[7];
  const float* Wo  = (const float*)d_in[8];
  const float* bo  = (const float*)d_in[9];
  float* out = (float*)d_out;

  // workspace layout: O [NB*SQ*DM] | K [NB*KVP*DM] | V [NB*KVP*DM]  (~175.6 MB)
  char* ws = (char*)d_ws;
  float* Ob = (float*)ws;
  float* Kb = (float*)(ws + (size_t)NB * SQ * DM * sizeof(float));
  float* Vb = Kb + (size_t)NB * KVP * DM;

  kv_proj_kernel<<<dim3(DM / 64, NB), 256, 0, stream>>>(ehs, Wk, Wv, Kb, Vb);
  style_proj_kernel<<<dim3(DM / 64, NB), 256, 0, stream>>>(sty, Wks, Wvs, Kb, Vb);
  fused_q_attn_kernel<<<dim3(SQ / 64, NH, NB), 256, 0, stream>>>(hs, Wq, Kb, Vb, Ob);
  out_proj_kernel<<<dim3(DM / 128, (NB * SQ) / 128), 256, 0, stream>>>(Ob, Wo, bo, out);
}

// Round 2
// 1660.579 us; speedup vs baseline: 2.4209x; 2.4209x over previous
//
#include <hip/hip_runtime.h>
#include <hip/hip_bf16.h>

#define NB 8
#define SQ 4096
#define DM 1280
#define NH 20
#define DH 64
#define SE 77
#define SS 4
#define CE 768
#define SKV 81
#define KVP 96
#define MTOT (NB * SQ)   // 32768

typedef short short8 __attribute__((ext_vector_type(8)));
typedef float f32x4 __attribute__((ext_vector_type(4)));

__device__ __forceinline__ ushort bfh(float x) {
  union { float f; uint u; } c; c.f = x;
  uint r = c.u + 0x7FFFu + ((c.u >> 16) & 1u);
  return (ushort)(r >> 16);
}
__device__ __forceinline__ float bff(ushort h) {
  union { uint u; float f; } c; c.u = ((uint)h) << 16;
  return c.f;
}

// ---------------------------------------------------------------------------
// Kernel 0: split Wq and Wo into bf16 hi/lo, TRANSPOSED to [n][k] so GEMM
// B-staging is a pure 16B copy (no cvt, no transpose in the hot loop).
// grid (20, 10, 2): n-block 64, k-block 128, which ∈ {Wq, Wo}.
// ---------------------------------------------------------------------------
__global__ __launch_bounds__(256) void wsplit_kernel(
    const float* __restrict__ Wq, const float* __restrict__ Wo,
    ushort* __restrict__ Whi, ushort* __restrict__ Wlo)
{
  const int which = blockIdx.z;
  const float* W = which ? Wo : Wq;
  ushort* hi = Whi + (size_t)which * DM * DM;
  ushort* lo = Wlo + (size_t)which * DM * DM;
  const int tid = threadIdx.x;
  const int n = blockIdx.x * 64 + (tid >> 2);
  const int k0 = blockIdx.y * 128 + (tid & 3) * 32;
  ushort hh[32], ll[32];
  #pragma unroll
  for (int i = 0; i < 32; ++i) {
    float x = W[(size_t)(k0 + i) * DM + n];
    hh[i] = bfh(x);
    ll[i] = bfh(x - bff(hh[i]));
  }
  #pragma unroll
  for (int i = 0; i < 32; i += 4) {
    *(ushort4*)&hi[(size_t)n * DM + k0 + i] = make_ushort4(hh[i], hh[i+1], hh[i+2], hh[i+3]);
    *(ushort4*)&lo[(size_t)n * DM + k0 + i] = make_ushort4(ll[i], ll[i+1], ll[i+2], ll[i+3]);
  }
}

// ---------------------------------------------------------------------------
// Kernel 1: bf16x3 MFMA GEMM, C[M x 1280] = A[M x 1280] @ W[1280 x 1280].
// MODE 0: C = 0.125 * (A@W)   (Q projection, attn scale folded in)
// MODE 1: C = A@W + bias      (output projection)
// Tile 128x128, BK=32, 4 waves (2x2 of 64x64), 16x16x32 bf16 MFMA.
// LDS is fragment-major: [frag][lane][8 bf16] -> every ds op is a permutation
// of lane-linear 16B, i.e. conflict-free. A split in-register during staging;
// W pre-split + pre-transposed so B staging is uint4 copy only.
// 3 MFMA per (i,j) pair: Ahi*Bhi + Ahi*Blo + Alo*Bhi (lo*lo dropped, ~2^-16).
// ---------------------------------------------------------------------------
template<int MODE>
__global__ __launch_bounds__(256) void mfma_gemm_kernel(
    const float* __restrict__ A, const ushort* __restrict__ Whi,
    const ushort* __restrict__ Wlo, const float* __restrict__ bias,
    float* __restrict__ C)
{
  __shared__ __align__(16) ushort aHs[8 * 64 * 8];
  __shared__ __align__(16) ushort aLs[8 * 64 * 8];
  __shared__ __align__(16) ushort bHs[8 * 64 * 8];
  __shared__ __align__(16) ushort bLs[8 * 64 * 8];

  const int tid = threadIdx.x;
  const int lane = tid & 63, w = tid >> 6;

  // XCD-aware bijective swizzle (nwg = 2560, %8 == 0); chunk per XCD shares
  // A-panels + whole W in that XCD's L2.
  const int cpx = gridDim.x >> 3;
  const int lin = blockIdx.x;
  const int swz = (lin & 7) * cpx + (lin >> 3);
  const int bm = swz / 10, bn = swz - bm * 10;
  const int m0 = bm * 128, n0 = bn * 128;

  // A staging: slot = (mf, L): m = mf*16 + (L&15), k = (L>>4)*8 .. +7
  const int amf0 = (tid >> 6) * 2;
  const int am_r = lane & 15, akg = lane >> 4;
  const float* aBase = A + (size_t)(m0 + am_r) * DM + akg * 8;

  // B staging: slot sid ∈ {tid, tid+256}: n = sid>>2, kg = sid&3
  const int bn0_ = (tid >> 2), bkg0 = (tid & 3);
  const int bn1_ = ((tid + 256) >> 2), bkg1 = ((tid + 256) & 3);

  f32x4 acc[4][4];
  #pragma unroll
  for (int i = 0; i < 4; ++i)
    #pragma unroll
    for (int j = 0; j < 4; ++j)
      acc[i][j] = (f32x4)(0.0f);

  const int wmf = (w >> 1) * 4, wnf = (w & 1) * 4;

  for (int kk = 0; kk < DM; kk += 32) {
    __syncthreads();
    // ---- stage A (fp32 -> hi/lo bf16) ----
    #pragma unroll
    for (int s = 0; s < 2; ++s) {
      const int mf = amf0 + s;
      const float* p = aBase + (size_t)mf * (16 * DM) + kk;
      float4 v0 = *(const float4*)p;
      float4 v1 = *(const float4*)(p + 4);
      float xv[8] = {v0.x, v0.y, v0.z, v0.w, v1.x, v1.y, v1.z, v1.w};
      ushort hh[8], ll[8];
      #pragma unroll
      for (int e = 0; e < 8; ++e) {
        hh[e] = bfh(xv[e]);
        ll[e] = bfh(xv[e] - bff(hh[e]));
      }
      uint4 hv = make_uint4(hh[0] | ((uint)hh[1] << 16), hh[2] | ((uint)hh[3] << 16),
                            hh[4] | ((uint)hh[5] << 16), hh[6] | ((uint)hh[7] << 16));
      uint4 lv = make_uint4(ll[0] | ((uint)ll[1] << 16), ll[2] | ((uint)ll[3] << 16),
                            ll[4] | ((uint)ll[5] << 16), ll[6] | ((uint)ll[7] << 16));
      *(uint4*)&aHs[(mf * 64 + lane) * 8] = hv;
      *(uint4*)&aLs[(mf * 64 + lane) * 8] = lv;
    }
    // ---- stage B (pure copy of pre-split transposed W) ----
    {
      size_t o0 = (size_t)(n0 + bn0_) * DM + kk + bkg0 * 8;
      size_t o1 = (size_t)(n0 + bn1_) * DM + kk + bkg1 * 8;
      uint4 h0 = *(const uint4*)(Whi + o0);
      uint4 l0 = *(const uint4*)(Wlo + o0);
      uint4 h1 = *(const uint4*)(Whi + o1);
      uint4 l1 = *(const uint4*)(Wlo + o1);
      int L0 = (bn0_ & 15) + bkg0 * 16, F0 = bn0_ >> 4;
      int L1 = (bn1_ & 15) + bkg1 * 16, F1 = bn1_ >> 4;
      *(uint4*)&bHs[(F0 * 64 + L0) * 8] = h0;
      *(uint4*)&bLs[(F0 * 64 + L0) * 8] = l0;
      *(uint4*)&bHs[(F1 * 64 + L1) * 8] = h1;
      *(uint4*)&bLs[(F1 * 64 + L1) * 8] = l1;
    }
    __syncthreads();
    // ---- compute: 48 MFMA / wave / k-step ----
    const short8* ap  = (const short8*)aHs;
    const short8* alp = (const short8*)aLs;
    const short8* bp  = (const short8*)bHs;
    const short8* blp = (const short8*)bLs;
    short8 ahf[4], alf[4];
    #pragma unroll
    for (int i = 0; i < 4; ++i) {
      ahf[i] = ap[(wmf + i) * 64 + lane];
      alf[i] = alp[(wmf + i) * 64 + lane];
    }
    #pragma unroll
    for (int j = 0; j < 4; ++j) {
      short8 bh = bp[(wnf + j) * 64 + lane];
      short8 bl = blp[(wnf + j) * 64 + lane];
      #pragma unroll
      for (int i = 0; i < 4; ++i) {
        acc[i][j] = __builtin_amdgcn_mfma_f32_16x16x32_bf16(ahf[i], bh, acc[i][j], 0, 0, 0);
        acc[i][j] = __builtin_amdgcn_mfma_f32_16x16x32_bf16(ahf[i], bl, acc[i][j], 0, 0, 0);
        acc[i][j] = __builtin_amdgcn_mfma_f32_16x16x32_bf16(alf[i], bh, acc[i][j], 0, 0, 0);
      }
    }
  }

  // ---- epilogue: C/D layout col = lane&15, row = (lane>>4)*4 + reg ----
  const int rbase = (lane >> 4) * 4, ccol = lane & 15;
  const int wm = m0 + (w >> 1) * 64, wn = n0 + (w & 1) * 64;
  #pragma unroll
  for (int j = 0; j < 4; ++j) {
    const int col = wn + j * 16 + ccol;
    const float bv = (MODE == 1) ? bias[col] : 0.0f;
    #pragma unroll
    for (int i = 0; i < 4; ++i) {
      #pragma unroll
      for (int r = 0; r < 4; ++r) {
        const int row = wm + i * 16 + rbase + r;
        float v = acc[i][j][r];
        if (MODE == 0) v *= 0.125f; else v += bv;
        C[(size_t)row * DM + col] = v;
      }
    }
  }
}

// ---------------------------------------------------------------------------
// Kernel 2: K/V projection for encoder rows 0..76. grid (DM/64, NB).
// ---------------------------------------------------------------------------
__global__ __launch_bounds__(256) void kv_proj_kernel(
    const float* __restrict__ ehs, const float* __restrict__ Wk,
    const float* __restrict__ Wv, float* __restrict__ Kb, float* __restrict__ Vb)
{
  const int n0 = blockIdx.x * 64;
  const int b  = blockIdx.y;
  const int tid = threadIdx.x;
  const int tx = tid & 15, ty = tid >> 4;
  const int r0 = ty * 5, c0 = tx * 4;

  __shared__ float sS[80][33];
  __shared__ float sK[32][64];
  __shared__ float sV[32][64];

  float accK[5][4] = {};
  float accV[5][4] = {};

  for (int kc = 0; kc < CE; kc += 32) {
    __syncthreads();
    for (int f = tid; f < 640; f += 256) {
      int row = f >> 3, c4 = (f & 7) << 2;
      float4 v = make_float4(0.f, 0.f, 0.f, 0.f);
      if (row < SE) v = *(const float4*)&ehs[(size_t)(b * SE + row) * CE + kc + c4];
      sS[row][c4 + 0] = v.x; sS[row][c4 + 1] = v.y;
      sS[row][c4 + 2] = v.z; sS[row][c4 + 3] = v.w;
    }
    for (int f = tid; f < 512; f += 256) {
      int r = f >> 4, c4 = (f & 15) << 2;
      *(float4*)&sK[r][c4] = *(const float4*)&Wk[(size_t)(kc + r) * DM + n0 + c4];
      *(float4*)&sV[r][c4] = *(const float4*)&Wv[(size_t)(kc + r) * DM + n0 + c4];
    }
    __syncthreads();
    #pragma unroll
    for (int k = 0; k < 32; ++k) {
      float a[5];
      #pragma unroll
      for (int i = 0; i < 5; ++i) a[i] = sS[r0 + i][k];
      float4 wk4 = *(float4*)&sK[k][c0];
      float4 wv4 = *(float4*)&sV[k][c0];
      float wk[4] = {wk4.x, wk4.y, wk4.z, wk4.w};
      float wv[4] = {wv4.x, wv4.y, wv4.z, wv4.w};
      #pragma unroll
      for (int i = 0; i < 5; ++i)
        #pragma unroll
        for (int j = 0; j < 4; ++j) {
          accK[i][j] += a[i] * wk[j];
          accV[i][j] += a[i] * wv[j];
        }
    }
  }
  #pragma unroll
  for (int i = 0; i < 5; ++i) {
    int r = r0 + i;
    if (r < SE) {
      *(float4*)&Kb[(size_t)(b * KVP + r) * DM + n0 + c0] =
          make_float4(accK[i][0], accK[i][1], accK[i][2], accK[i][3]);
      *(float4*)&Vb[(size_t)(b * KVP + r) * DM + n0 + c0] =
          make_float4(accV[i][0], accV[i][1], accV[i][2], accV[i][3]);
    }
  }
}

// ---------------------------------------------------------------------------
// Kernel 3: style-token K/V projection (rows 77..80). grid (DM/64, NB).
// ---------------------------------------------------------------------------
__global__ __launch_bounds__(256) void style_proj_kernel(
    const float* __restrict__ sty, const float* __restrict__ Wks,
    const float* __restrict__ Wvs, float* __restrict__ Kb, float* __restrict__ Vb)
{
  const int n0 = blockIdx.x * 64;
  const int b  = blockIdx.y;
  const int tid = threadIdx.x;
  __shared__ float sT[SS][CE];
  for (int f = tid; f < SS * (CE / 4); f += 256) {
    int row = f / (CE / 4), c4 = (f % (CE / 4)) << 2;
    *(float4*)&sT[row][c4] = *(const float4*)&sty[(size_t)(b * SS + row) * CE + c4];
  }
  __syncthreads();
  const int row = tid >> 6;
  const int col = n0 + (tid & 63);
  float aK = 0.f, aV = 0.f;
  for (int c = 0; c < CE; ++c) {
    float s = sT[row][c];
    aK += s * Wks[(size_t)c * DM + col];
    aV += s * Wvs[(size_t)c * DM + col];
  }
  Kb[(size_t)(b * KVP + SE + row) * DM + col] = aK;
  Vb[(size_t)(b * KVP + SE + row) * DM + col] = aV;
}

// ---------------------------------------------------------------------------
// Kernel 4: attention only (Q already projected & pre-scaled, in Qb).
// grid (SQ/64, NH, NB), 256 threads. Q staged transposed -> conflict-free
// per-lane column reads in the score phase.
// ---------------------------------------------------------------------------
__global__ __launch_bounds__(256) void attn_kernel(
    const float* __restrict__ Qb, const float* __restrict__ Kb,
    const float* __restrict__ Vb, float* __restrict__ Ob)
{
  const int q0 = blockIdx.x * 64;
  const int h  = blockIdx.y;
  const int b  = blockIdx.z;
  const int tid = threadIdx.x;
  const int tx = tid & 15, ty = tid >> 4;
  const int r0 = ty * 4, c0 = tx * 4;

  __shared__ float qT[64][66];   // [d][q-row]
  __shared__ float kvL[84][64];  // K then V (rows 81..83 zero pad for K)
  __shared__ float sL[64][85];   // scores -> probs; [.. ][84] = 1/sum

  for (int f = tid; f < 64 * 16; f += 256) {
    int row = f >> 4, c4 = (f & 15) << 2;
    float4 v = *(const float4*)&Qb[(size_t)(b * SQ + q0 + row) * DM + h * DH + c4];
    qT[c4 + 0][row] = v.x; qT[c4 + 1][row] = v.y;
    qT[c4 + 2][row] = v.z; qT[c4 + 3][row] = v.w;
  }
  for (int f = tid; f < 84 * 16; f += 256) {
    int kk = f >> 4, d4 = (f & 15) << 2;
    float4 v = make_float4(0.f, 0.f, 0.f, 0.f);
    if (kk < SKV) v = *(const float4*)&Kb[(size_t)(b * KVP + kk) * DM + h * DH + d4];
    *(float4*)&kvL[kk][d4] = v;
  }
  __syncthreads();

  // ---- scores: lane = q-row; wave w handles k = w, w+4, ... ----
  const int lane = tid & 63, w = tid >> 6;
  float sc[21];
  #pragma unroll
  for (int i = 0; i < 21; ++i) sc[i] = 0.f;
  #pragma unroll
  for (int d = 0; d < DH; d += 4) {
    float qv0 = qT[d + 0][lane], qv1 = qT[d + 1][lane];
    float qv2 = qT[d + 2][lane], qv3 = qT[d + 3][lane];
    #pragma unroll
    for (int ki = 0; ki < 21; ++ki) {
      float4 kv = *(float4*)&kvL[w + 4 * ki][d];   // wave-uniform: broadcast
      sc[ki] += qv0 * kv.x + qv1 * kv.y + qv2 * kv.z + qv3 * kv.w;
    }
  }
  #pragma unroll
  for (int ki = 0; ki < 21; ++ki) sL[lane][w + 4 * ki] = sc[ki];
  __syncthreads();

  // ---- V staging (all threads) + softmax (wave 0) ----
  for (int f = tid; f < SKV * 16; f += 256) {
    int kk = f >> 4, d4 = (f & 15) << 2;
    *(float4*)&kvL[kk][d4] = *(const float4*)&Vb[(size_t)(b * KVP + kk) * DM + h * DH + d4];
  }
  if (tid < 64) {
    float m = -1e30f;
    for (int k = 0; k < SKV; ++k) m = fmaxf(m, sL[tid][k]);
    float sum = 0.f;
    for (int k = 0; k < SKV; ++k) {
      float e = __expf(sL[tid][k] - m);
      sL[tid][k] = e;
      sum += e;
    }
    sL[tid][84] = 1.0f / sum;
  }
  __syncthreads();

  // ---- O = P @ V ----
  float o[4][4] = {};
  for (int k = 0; k < SKV; ++k) {
    float p0 = sL[r0 + 0][k], p1 = sL[r0 + 1][k];
    float p2 = sL[r0 + 2][k], p3 = sL[r0 + 3][k];
    float4 v4 = *(float4*)&kvL[k][c0];
    float vj[4] = {v4.x, v4.y, v4.z, v4.w};
    #pragma unroll
    for (int j = 0; j < 4; ++j) {
      o[0][j] += p0 * vj[j];
      o[1][j] += p1 * vj[j];
      o[2][j] += p2 * vj[j];
      o[3][j] += p3 * vj[j];
    }
  }
  #pragma unroll
  for (int i = 0; i < 4; ++i) {
    float inv = sL[r0 + i][84];
    *(float4*)&Ob[(size_t)(b * SQ + q0 + r0 + i) * DM + h * DH + c0] =
        make_float4(o[i][0] * inv, o[i][1] * inv, o[i][2] * inv, o[i][3] * inv);
  }
}

// ---------------------------------------------------------------------------
extern "C" void kernel_launch(void* const* d_in, const int* in_sizes, int n_in,
                              void* d_out, int out_size, void* d_ws, size_t ws_size,
                              hipStream_t stream) {
  const float* hs  = (const float*)d_in[0];
  const float* ehs = (const float*)d_in[1];
  const float* sty = (const float*)d_in[2];
  const float* Wq  = (const float*)d_in[3];
  const float* Wk  = (const float*)d_in[4];
  const float* Wv  = (const float*)d_in[5];
  const float* Wks = (const float*)d_in[6];
  const float* Wvs = (const float*)d_in[7];
  const float* Wo  = (const float*)d_in[8];
  const float* bo  = (const float*)d_in[9];
  float* out = (float*)d_out;

  // ws: Ob [32768x1280]f32 | Kb | Vb | Whi [2x1280x1280]bf16 | Wlo  (~180 MB)
  char* ws = (char*)d_ws;
  float* Ob = (float*)ws;
  float* Kb = (float*)(ws + (size_t)MTOT * DM * sizeof(float));
  float* Vb = Kb + (size_t)NB * KVP * DM;
  ushort* Whi = (ushort*)(Vb + (size_t)NB * KVP * DM);
  ushort* Wlo = Whi + (size_t)2 * DM * DM;
  float* Qb = (float*)d_out;   // d_out doubles as Q scratch (fully rewritten later)

  wsplit_kernel<<<dim3(20, 10, 2), 256, 0, stream>>>(Wq, Wo, Whi, Wlo);
  kv_proj_kernel<<<dim3(DM / 64, NB), 256, 0, stream>>>(ehs, Wk, Wv, Kb, Vb);
  style_proj_kernel<<<dim3(DM / 64, NB), 256, 0, stream>>>(sty, Wks, Wvs, Kb, Vb);
  mfma_gemm_kernel<0><<<dim3((MTOT / 128) * 10), 256, 0, stream>>>(hs, Whi, Wlo, nullptr, Qb);
  attn_kernel<<<dim3(SQ / 64, NH, NB), 256, 0, stream>>>(Qb, Kb, Vb, Ob);
  mfma_gemm_kernel<1><<<dim3((MTOT / 128) * 10), 256, 0, stream>>>(
      Ob, Whi + (size_t)DM * DM, Wlo + (size_t)DM * DM, bo, out);
}